// Round 1
// baseline (996.438 us; speedup 1.0000x reference)
//
#include <hip/hip_runtime.h>

#define EMBED 128

// ---------------- CSR build ----------------

__global__ void hist_kernel(const int* __restrict__ row, int* __restrict__ hist, int E) {
    int e = blockIdx.x * blockDim.x + threadIdx.x;
    if (e < E) atomicAdd(&hist[row[e]], 1);
}

// per-256-chunk exclusive scan; chunk totals -> bsums
__global__ void scan1(const int* __restrict__ hist, int* __restrict__ rs,
                      int* __restrict__ bsums, int N) {
    __shared__ int s[256];
    int i = blockIdx.x * 256 + threadIdx.x;
    int x = (i < N) ? hist[i] : 0;
    s[threadIdx.x] = x;
    __syncthreads();
    for (int off = 1; off < 256; off <<= 1) {
        int t = (threadIdx.x >= off) ? s[threadIdx.x - off] : 0;
        __syncthreads();
        s[threadIdx.x] += t;
        __syncthreads();
    }
    if (i < N) rs[i] = s[threadIdx.x] - x;        // exclusive, chunk-local
    if (threadIdx.x == 255) bsums[blockIdx.x] = s[255];
}

// exclusive scan of block sums (handles nb > 1024 via carry loop; nb=586 here)
__global__ void scan2(int* __restrict__ bsums, int nb) {
    __shared__ int s[1024];
    __shared__ int carry;
    if (threadIdx.x == 0) carry = 0;
    __syncthreads();
    for (int base = 0; base < nb; base += 1024) {
        int i = base + threadIdx.x;
        int x = (i < nb) ? bsums[i] : 0;
        s[threadIdx.x] = x;
        __syncthreads();
        for (int off = 1; off < 1024; off <<= 1) {
            int t = (threadIdx.x >= off) ? s[threadIdx.x - off] : 0;
            __syncthreads();
            s[threadIdx.x] += t;
            __syncthreads();
        }
        if (i < nb) bsums[i] = s[threadIdx.x] - x + carry;
        __syncthreads();
        if (threadIdx.x == 0) carry += s[1023];
        __syncthreads();
    }
}

__global__ void scan3(int* __restrict__ rs, const int* __restrict__ bsums,
                      int* __restrict__ cursor, int N, int E) {
    int i = blockIdx.x * blockDim.x + threadIdx.x;
    if (i < N) {
        int v = rs[i] + bsums[i >> 8];
        rs[i] = v;
        cursor[i] = v;
    }
    if (i == 0) rs[N] = E;
}

__global__ void scatter_kernel(const int* __restrict__ row, const int* __restrict__ col,
                               const float* __restrict__ val, int* __restrict__ cursor,
                               int* __restrict__ ccol, float* __restrict__ cval, int E) {
    int e = blockIdx.x * blockDim.x + threadIdx.x;
    if (e < E) {
        int r = row[e];
        int pos = atomicAdd(&cursor[r], 1);
        ccol[pos] = col[e];
        cval[pos] = val[e];
    }
}

// ---------------- SpMM: one wave per row, float2 per lane ----------------

__global__ void spmm_kernel(const int* __restrict__ rs, const int* __restrict__ ccol,
                            const float* __restrict__ cval,
                            const float* __restrict__ hin,   // null => read embeddings
                            const float* __restrict__ uE, const float* __restrict__ iE,
                            float* __restrict__ hout, int N, int userNum) {
    int wave = (int)((blockIdx.x * blockDim.x + threadIdx.x) >> 6);
    int lane = threadIdx.x & 63;
    if (wave >= N) return;
    int s = rs[wave], e = rs[wave + 1];
    float2 acc = make_float2(0.f, 0.f);
    for (int k = s; k < e; ++k) {
        float v = cval[k];
        int   c = ccol[k];
        const float* src;
        if (hin) {
            src = hin + (size_t)c * EMBED;
        } else {
            src = (c < userNum) ? (uE + (size_t)c * EMBED)
                                : (iE + (size_t)(c - userNum) * EMBED);
        }
        float2 x = *(const float2*)(src + 2 * lane);
        acc.x += v * x.x;
        acc.y += v * x.y;
    }
    *(float2*)(hout + (size_t)wave * EMBED + 2 * lane) = acc;
}

// ---------------- gather selected rows into accU/accV ----------------

__global__ void gather_kernel(const float* __restrict__ h,   // null => embeddings
                              const float* __restrict__ uE, const float* __restrict__ iE,
                              const int* __restrict__ uIdx, const int* __restrict__ vIdx,
                              float* __restrict__ accU, float* __restrict__ accV,
                              int B, int userNum, int init) {
    int wave = (int)((blockIdx.x * blockDim.x + threadIdx.x) >> 6);
    int lane = threadIdx.x & 63;
    if (wave >= 2 * B) return;
    const float* src;
    float* dst;
    if (wave < B) {
        int n = uIdx[wave];
        src = h ? (h + (size_t)n * EMBED) : (uE + (size_t)n * EMBED);
        dst = accU + (size_t)wave * EMBED;
    } else {
        int b = wave - B;
        int n = vIdx[b];
        src = h ? (h + (size_t)(userNum + n) * EMBED) : (iE + (size_t)n * EMBED);
        dst = accV + (size_t)b * EMBED;
    }
    float2 x = *(const float2*)(src + 2 * lane);
    float2 d;
    if (init) { d.x = 0.f; d.y = 0.f; }
    else      { d = *(const float2*)(dst + 2 * lane); }
    d.x += x.x;
    d.y += x.y;
    *(float2*)(dst + 2 * lane) = d;
}

__global__ void dot_kernel(const float* __restrict__ accU, const float* __restrict__ accV,
                           float* __restrict__ out, int B) {
    int wave = (int)((blockIdx.x * blockDim.x + threadIdx.x) >> 6);
    int lane = threadIdx.x & 63;
    if (wave >= B) return;
    float2 a = *(const float2*)(accU + (size_t)wave * EMBED + 2 * lane);
    float2 b = *(const float2*)(accV + (size_t)wave * EMBED + 2 * lane);
    float v = a.x * b.x + a.y * b.y;
    #pragma unroll
    for (int off = 32; off > 0; off >>= 1) v += __shfl_down(v, off);
    if (lane == 0) out[wave] = v * (1.f / 16.f);   // (acc/4)·(acc/4)
}

// ---------------- launch ----------------

extern "C" void kernel_launch(void* const* d_in, const int* in_sizes, int n_in,
                              void* d_out, int out_size, void* d_ws, size_t ws_size,
                              hipStream_t stream) {
    const float* uE      = (const float*)d_in[0];
    const float* iE      = (const float*)d_in[1];
    const float* L_val   = (const float*)d_in[2];
    const int*   L_row   = (const int*)d_in[3];
    const int*   L_col   = (const int*)d_in[4];
    const int*   userIdx = (const int*)d_in[5];
    const int*   itemIdx = (const int*)d_in[6];

    const int userNum = in_sizes[0] / EMBED;   // 100000
    const int itemNum = in_sizes[1] / EMBED;   // 50000
    const int N = userNum + itemNum;           // 150000
    const int E = in_sizes[2];                 // 2000000
    const int B = in_sizes[5];                 // 16384
    float* out = (float*)d_out;

    // workspace carve-out (1 KiB-aligned regions), ~189 MB total
    char* ws = (char*)d_ws;
    size_t off = 0;
    auto alloc = [&](size_t bytes) -> void* {
        void* p = ws + off;
        off += (bytes + 1023) & ~(size_t)1023;
        return p;
    };
    float* h_a    = (float*)alloc((size_t)N * EMBED * 4);
    float* h_b    = (float*)alloc((size_t)N * EMBED * 4);
    float* cval   = (float*)alloc((size_t)E * 4);
    int*   ccol   = (int*)  alloc((size_t)E * 4);
    int*   rs     = (int*)  alloc((size_t)(N + 1) * 4);
    int*   cursor = (int*)  alloc((size_t)N * 4);
    int*   hist   = (int*)  alloc((size_t)N * 4);
    int*   bsums  = (int*)  alloc(8192);
    float* accU   = (float*)alloc((size_t)B * EMBED * 4);
    float* accV   = (float*)alloc((size_t)B * EMBED * 4);
    (void)off; (void)ws_size; (void)n_in; (void)out_size;

    const int tb = 256;

    // CSR build (deterministic histogram+scan; within-row order nondet, fp32-sum safe)
    hipMemsetAsync(hist, 0, (size_t)N * 4, stream);
    hist_kernel<<<(E + tb - 1) / tb, tb, 0, stream>>>(L_row, hist, E);
    const int nb = (N + 255) / 256;
    scan1<<<nb, 256, 0, stream>>>(hist, rs, bsums, N);
    scan2<<<1, 1024, 0, stream>>>(bsums, nb);
    scan3<<<(N + tb - 1) / tb, tb, 0, stream>>>(rs, bsums, cursor, N, E);
    scatter_kernel<<<(E + tb - 1) / tb, tb, 0, stream>>>(L_row, L_col, L_val, cursor,
                                                         ccol, cval, E);

    // propagation: h1 = L*feats; h2 = L*h1; h3 = L*h2; gather acc per layer
    const int spmm_blocks = (N + 3) / 4;        // 4 waves (rows) per 256-thread block
    const int gb = (2 * B + 3) / 4;

    spmm_kernel<<<spmm_blocks, 256, 0, stream>>>(rs, ccol, cval, nullptr, uE, iE, h_a, N, userNum);
    gather_kernel<<<gb, 256, 0, stream>>>(nullptr, uE, iE, userIdx, itemIdx, accU, accV, B, userNum, 1);
    gather_kernel<<<gb, 256, 0, stream>>>(h_a, uE, iE, userIdx, itemIdx, accU, accV, B, userNum, 0);

    spmm_kernel<<<spmm_blocks, 256, 0, stream>>>(rs, ccol, cval, h_a, uE, iE, h_b, N, userNum);
    gather_kernel<<<gb, 256, 0, stream>>>(h_b, uE, iE, userIdx, itemIdx, accU, accV, B, userNum, 0);

    spmm_kernel<<<spmm_blocks, 256, 0, stream>>>(rs, ccol, cval, h_b, uE, iE, h_a, N, userNum);
    gather_kernel<<<gb, 256, 0, stream>>>(h_a, uE, iE, userIdx, itemIdx, accU, accV, B, userNum, 0);

    dot_kernel<<<(B + 3) / 4, 256, 0, stream>>>(accU, accV, out, B);
}

// Round 2
// 672.922 us; speedup vs baseline: 1.4808x; 1.4808x over previous
//
#include <hip/hip_runtime.h>

#define EMBED 128

// ---------------- CSR build ----------------

__global__ void hist_kernel(const int* __restrict__ row, int* __restrict__ hist, int E) {
    int e = blockIdx.x * blockDim.x + threadIdx.x;
    if (e < E) atomicAdd(&hist[row[e]], 1);
}

// per-256-chunk exclusive scan; chunk totals -> bsums
__global__ void scan1(const int* __restrict__ hist, int* __restrict__ rs,
                      int* __restrict__ bsums, int N) {
    __shared__ int s[256];
    int i = blockIdx.x * 256 + threadIdx.x;
    int x = (i < N) ? hist[i] : 0;
    s[threadIdx.x] = x;
    __syncthreads();
    for (int off = 1; off < 256; off <<= 1) {
        int t = (threadIdx.x >= off) ? s[threadIdx.x - off] : 0;
        __syncthreads();
        s[threadIdx.x] += t;
        __syncthreads();
    }
    if (i < N) rs[i] = s[threadIdx.x] - x;        // exclusive, chunk-local
    if (threadIdx.x == 255) bsums[blockIdx.x] = s[255];
}

__global__ void scan2(int* __restrict__ bsums, int nb) {
    __shared__ int s[1024];
    __shared__ int carry;
    if (threadIdx.x == 0) carry = 0;
    __syncthreads();
    for (int base = 0; base < nb; base += 1024) {
        int i = base + threadIdx.x;
        int x = (i < nb) ? bsums[i] : 0;
        s[threadIdx.x] = x;
        __syncthreads();
        for (int off = 1; off < 1024; off <<= 1) {
            int t = (threadIdx.x >= off) ? s[threadIdx.x - off] : 0;
            __syncthreads();
            s[threadIdx.x] += t;
            __syncthreads();
        }
        if (i < nb) bsums[i] = s[threadIdx.x] - x + carry;
        __syncthreads();
        if (threadIdx.x == 0) carry += s[1023];
        __syncthreads();
    }
}

__global__ void scan3(int* __restrict__ rs, const int* __restrict__ bsums,
                      int* __restrict__ cursor, int N, int E) {
    int i = blockIdx.x * blockDim.x + threadIdx.x;
    if (i < N) {
        int v = rs[i] + bsums[i >> 8];
        rs[i] = v;
        cursor[i] = v;
    }
    if (i == 0) rs[N] = E;
}

// pack (col, val) into int2 -> one 8B random write, one 8B load later
__global__ void scatter_kernel(const int* __restrict__ row, const int* __restrict__ col,
                               const float* __restrict__ val, int* __restrict__ cursor,
                               int2* __restrict__ edges, int E) {
    int e = blockIdx.x * blockDim.x + threadIdx.x;
    if (e < E) {
        int r = row[e];
        int pos = atomicAdd(&cursor[r], 1);
        edges[pos] = make_int2(col[e], __float_as_int(val[e]));
    }
}

// ---------------- SpMM: 2 rows per wave (32 lanes each), float4/lane ----------------
// Edge loop strip-mined into predicated chunks of 4: all loads issued before FMAs.

template <bool FIRST>
__global__ void spmm_kernel(const int* __restrict__ rs, const int2* __restrict__ edges,
                            const float* __restrict__ hin,
                            const float* __restrict__ uE, const float* __restrict__ iE,
                            float* __restrict__ hout, int N, int userNum) {
    int gid  = blockIdx.x * blockDim.x + threadIdx.x;
    int wave = gid >> 6;
    int lane = threadIdx.x & 63;
    int half = lane >> 5;
    int l32  = lane & 31;
    int row  = wave * 2 + half;
    if (row >= N) return;
    int s = rs[row], e = rs[row + 1];
    float4 acc = make_float4(0.f, 0.f, 0.f, 0.f);
    for (int k = s; k < e; k += 4) {
        float4 x[4];
        float  v[4];
        #pragma unroll
        for (int j = 0; j < 4; ++j) {
            bool ok  = (k + j) < e;
            int  idx = ok ? (k + j) : s;
            int2 ed  = edges[idx];
            int  c   = ed.x;
            v[j]     = ok ? __int_as_float(ed.y) : 0.f;
            const float* src;
            if (FIRST) {
                src = (c < userNum) ? (uE + (size_t)c * EMBED)
                                    : (iE + (size_t)(c - userNum) * EMBED);
            } else {
                src = hin + (size_t)c * EMBED;
            }
            x[j] = *(const float4*)(src + 4 * l32);
        }
        #pragma unroll
        for (int j = 0; j < 4; ++j) {
            acc.x += v[j] * x[j].x;
            acc.y += v[j] * x[j].y;
            acc.z += v[j] * x[j].z;
            acc.w += v[j] * x[j].w;
        }
    }
    *(float4*)(hout + (size_t)row * EMBED + 4 * l32) = acc;
}

// layer-3 SpMM restricted to the 2B sampled rows; accumulates into accU/accV
__global__ void spmm_sel_kernel(const int* __restrict__ rs, const int2* __restrict__ edges,
                                const float* __restrict__ hin,
                                const int* __restrict__ uIdx, const int* __restrict__ vIdx,
                                float* __restrict__ accU, float* __restrict__ accV,
                                int B, int userNum) {
    int gid  = blockIdx.x * blockDim.x + threadIdx.x;
    int wave = gid >> 6;
    int lane = threadIdx.x & 63;
    int half = lane >> 5;
    int l32  = lane & 31;
    int b    = wave * 2 + half;
    if (b >= 2 * B) return;
    int row;
    float* dst;
    if (b < B) {
        row = uIdx[b];
        dst = accU + (size_t)b * EMBED;
    } else {
        row = userNum + vIdx[b - B];
        dst = accV + (size_t)(b - B) * EMBED;
    }
    int s = rs[row], e = rs[row + 1];
    float4 acc = make_float4(0.f, 0.f, 0.f, 0.f);
    for (int k = s; k < e; k += 4) {
        float4 x[4];
        float  v[4];
        #pragma unroll
        for (int j = 0; j < 4; ++j) {
            bool ok  = (k + j) < e;
            int  idx = ok ? (k + j) : s;
            int2 ed  = edges[idx];
            v[j]     = ok ? __int_as_float(ed.y) : 0.f;
            x[j]     = *(const float4*)(hin + (size_t)ed.x * EMBED + 4 * l32);
        }
        #pragma unroll
        for (int j = 0; j < 4; ++j) {
            acc.x += v[j] * x[j].x;
            acc.y += v[j] * x[j].y;
            acc.z += v[j] * x[j].z;
            acc.w += v[j] * x[j].w;
        }
    }
    float4* dp = (float4*)(dst + 4 * l32);
    float4 d = *dp;
    d.x += acc.x; d.y += acc.y; d.z += acc.z; d.w += acc.w;
    *dp = d;
}

// acc(layers 0..2) = emb + h1 + h2 at the sampled rows, single write
__global__ void gather_fused(const float* __restrict__ uE, const float* __restrict__ iE,
                             const float* __restrict__ h1, const float* __restrict__ h2,
                             const int* __restrict__ uIdx, const int* __restrict__ vIdx,
                             float* __restrict__ accU, float* __restrict__ accV,
                             int B, int userNum) {
    int gid  = blockIdx.x * blockDim.x + threadIdx.x;
    int wave = gid >> 6;
    int lane = threadIdx.x & 63;
    int half = lane >> 5;
    int l32  = lane & 31;
    int b    = wave * 2 + half;
    if (b >= 2 * B) return;
    const float* emb;
    size_t ro;
    float* dst;
    if (b < B) {
        int u = uIdx[b];
        emb = uE + (size_t)u * EMBED;
        ro  = (size_t)u * EMBED;
        dst = accU + (size_t)b * EMBED;
    } else {
        int it = vIdx[b - B];
        emb = iE + (size_t)it * EMBED;
        ro  = (size_t)(userNum + it) * EMBED;
        dst = accV + (size_t)(b - B) * EMBED;
    }
    float4 a  = *(const float4*)(emb + 4 * l32);
    float4 x1 = *(const float4*)(h1 + ro + 4 * l32);
    float4 x2 = *(const float4*)(h2 + ro + 4 * l32);
    a.x += x1.x + x2.x;
    a.y += x1.y + x2.y;
    a.z += x1.z + x2.z;
    a.w += x1.w + x2.w;
    *(float4*)(dst + 4 * l32) = a;
}

__global__ void dot_kernel(const float* __restrict__ accU, const float* __restrict__ accV,
                           float* __restrict__ out, int B) {
    int gid  = blockIdx.x * blockDim.x + threadIdx.x;
    int wave = gid >> 6;
    int lane = threadIdx.x & 63;
    int half = lane >> 5;
    int l32  = lane & 31;
    int b    = wave * 2 + half;
    if (b >= B) return;
    float4 a = *(const float4*)(accU + (size_t)b * EMBED + 4 * l32);
    float4 v = *(const float4*)(accV + (size_t)b * EMBED + 4 * l32);
    float s = a.x * v.x + a.y * v.y + a.z * v.z + a.w * v.w;
    #pragma unroll
    for (int off = 16; off > 0; off >>= 1) s += __shfl_down(s, off, 32);
    if (l32 == 0) out[b] = s * (1.f / 16.f);   // (acc/4)·(acc/4)
}

// ---------------- launch ----------------

extern "C" void kernel_launch(void* const* d_in, const int* in_sizes, int n_in,
                              void* d_out, int out_size, void* d_ws, size_t ws_size,
                              hipStream_t stream) {
    const float* uE      = (const float*)d_in[0];
    const float* iE      = (const float*)d_in[1];
    const float* L_val   = (const float*)d_in[2];
    const int*   L_row   = (const int*)d_in[3];
    const int*   L_col   = (const int*)d_in[4];
    const int*   userIdx = (const int*)d_in[5];
    const int*   itemIdx = (const int*)d_in[6];

    const int userNum = in_sizes[0] / EMBED;   // 100000
    const int itemNum = in_sizes[1] / EMBED;   // 50000
    const int N = userNum + itemNum;           // 150000
    const int E = in_sizes[2];                 // 2000000
    const int B = in_sizes[5];                 // 16384
    float* out = (float*)d_out;

    char* ws = (char*)d_ws;
    size_t off = 0;
    auto alloc = [&](size_t bytes) -> void* {
        void* p = ws + off;
        off += (bytes + 1023) & ~(size_t)1023;
        return p;
    };
    float* h_a    = (float*)alloc((size_t)N * EMBED * 4);
    float* h_b    = (float*)alloc((size_t)N * EMBED * 4);
    int2*  edges  = (int2*) alloc((size_t)E * 8);
    int*   rs     = (int*)  alloc((size_t)(N + 1) * 4);
    int*   cursor = (int*)  alloc((size_t)N * 4);
    int*   hist   = (int*)  alloc((size_t)N * 4);
    int*   bsums  = (int*)  alloc(8192);
    float* accU   = (float*)alloc((size_t)B * EMBED * 4);
    float* accV   = (float*)alloc((size_t)B * EMBED * 4);
    (void)off; (void)ws_size; (void)n_in; (void)out_size;

    const int tb = 256;

    // CSR build
    hipMemsetAsync(hist, 0, (size_t)N * 4, stream);
    hist_kernel<<<(E + tb - 1) / tb, tb, 0, stream>>>(L_row, hist, E);
    const int nb = (N + 255) / 256;
    scan1<<<nb, 256, 0, stream>>>(hist, rs, bsums, N);
    scan2<<<1, 1024, 0, stream>>>(bsums, nb);
    scan3<<<(N + tb - 1) / tb, tb, 0, stream>>>(rs, bsums, cursor, N, E);
    scatter_kernel<<<(E + tb - 1) / tb, tb, 0, stream>>>(L_row, L_col, L_val, cursor,
                                                         edges, E);

    // propagation
    const int spmm_blocks = (N + 7) / 8;        // 8 rows per 256-thread block
    spmm_kernel<true ><<<spmm_blocks, 256, 0, stream>>>(rs, edges, nullptr, uE, iE, h_a, N, userNum);
    spmm_kernel<false><<<spmm_blocks, 256, 0, stream>>>(rs, edges, h_a, uE, iE, h_b, N, userNum);

    const int gb = (2 * B + 7) / 8;
    gather_fused<<<gb, 256, 0, stream>>>(uE, iE, h_a, h_b, userIdx, itemIdx,
                                         accU, accV, B, userNum);
    spmm_sel_kernel<<<gb, 256, 0, stream>>>(rs, edges, h_b, userIdx, itemIdx,
                                            accU, accV, B, userNum);

    dot_kernel<<<(B + 7) / 8, 256, 0, stream>>>(accU, accV, out, B);
}